// Round 10
// baseline (256.061 us; speedup 1.0000x reference)
//
#include <hip/hip_runtime.h>

#define THREADS   256
#define BLOCKS    2048   // 2048 blocks * 4 waves = 8192 waves
#define CHUNKS    16     // per wave; 2048*4*16*64 float4 = 8,388,608 = (512*65536)/4
#define NT_CHUNKS 12     // chunks 0..11 via nt VGPR pipeline
#define PIPE      6      // 12 nt loads in flight per wave
// chunks 12..15 via global_load_lds DMA (4 buffers x 2KB per wave)

typedef float f32x4 __attribute__((ext_vector_type(4)));

__global__ __launch_bounds__(THREADS) void dot_partial_kernel(
        const f32x4* __restrict__ a,
        const f32x4* __restrict__ b,
        float* __restrict__ partial) {
    // [wave][dma_chunk][a:0..1023 | b:1024..2047]
    __shared__ __align__(16) char lds[4][4][2048];
    __shared__ float smem_red[4];

    const int wave = threadIdx.x >> 6;
    const int lane = threadIdx.x & 63;
    const long long wc0 = ((long long)blockIdx.x * 4 + wave) * CHUNKS;

    // --- nt prologue: fill the VGPR pipeline (12 loads in flight) ---
    f32x4 va[PIPE], vb[PIPE];
    #pragma unroll
    for (int i = 0; i < PIPE; ++i) {
        const long long g = (wc0 + i) * 64 + lane;
        va[i] = __builtin_nontemporal_load(a + g);
        vb[i] = __builtin_nontemporal_load(b + g);
    }

    // --- issue all DMA chunks now; they stream during the nt main loop.
    // Issued BEFORE the loop refills -> older in vmcnt FIFO -> retired for
    // free by the time the last nt consume waits. Per-wave private LDS.
    #pragma unroll
    for (int c = 0; c < 4; ++c) {
        const long long g = (wc0 + NT_CHUNKS + c) * 64 + lane;
        __builtin_amdgcn_global_load_lds(
            (const __attribute__((address_space(1))) void*)(a + g),
            (__attribute__((address_space(3))) void*)&lds[wave][c][0], 16, 0, 0);
        __builtin_amdgcn_global_load_lds(
            (const __attribute__((address_space(1))) void*)(b + g),
            (__attribute__((address_space(3))) void*)&lds[wave][c][1024], 16, 0, 0);
    }

    // --- nt main loop ---
    f32x4 acc0 = (f32x4)0.f, acc1 = (f32x4)0.f;
    #pragma unroll
    for (int i = 0; i < NT_CHUNKS; ++i) {
        const int slot = i % PIPE;
        if (i & 1) acc1 += va[slot] * vb[slot];
        else       acc0 += va[slot] * vb[slot];
        if (i + PIPE < NT_CHUNKS) {
            const long long g = (wc0 + i + PIPE) * 64 + lane;
            va[slot] = __builtin_nontemporal_load(a + g);
            vb[slot] = __builtin_nontemporal_load(b + g);
        }
    }

    // --- drain DMAs (normally already retired) and consume from LDS ---
    __asm__ volatile("s_waitcnt vmcnt(0)" ::: "memory");
    #pragma unroll
    for (int c = 0; c < 4; ++c) {
        f32x4 av = *(const f32x4*)&lds[wave][c][lane * 16];
        f32x4 bv = *(const f32x4*)&lds[wave][c][1024 + lane * 16];
        if (c & 1) acc1 += av * bv;
        else       acc0 += av * bv;
    }

    f32x4 accv = acc0 + acc1;
    float s = (accv.x + accv.y) + (accv.z + accv.w);

    // wave-64 shuffle reduction
    #pragma unroll
    for (int off = 32; off > 0; off >>= 1)
        s += __shfl_down(s, off, 64);

    if (lane == 0) smem_red[wave] = s;
    __syncthreads();

    if (threadIdx.x == 0) {
        float t = 0.f;
        #pragma unroll
        for (int w = 0; w < 4; ++w) t += smem_red[w];
        partial[blockIdx.x] = t;
    }
}

__global__ __launch_bounds__(256) void final_reduce_kernel(
        const float* __restrict__ partial,
        float* __restrict__ out,
        int np, float inv_n) {
    float s = 0.f;
    for (int i = threadIdx.x; i < np; i += 256) s += partial[i];

    #pragma unroll
    for (int off = 32; off > 0; off >>= 1)
        s += __shfl_down(s, off, 64);

    __shared__ float smem[4];
    const int lane = threadIdx.x & 63;
    const int wave = threadIdx.x >> 6;
    if (lane == 0) smem[wave] = s;
    __syncthreads();

    if (threadIdx.x == 0) {
        float t = 0.f;
        #pragma unroll
        for (int w = 0; w < 4; ++w) t += smem[w];
        out[0] = 1.0f - t * inv_n;
    }
}

extern "C" void kernel_launch(void* const* d_in, const int* in_sizes, int n_in,
                              void* d_out, int out_size, void* d_ws, size_t ws_size,
                              hipStream_t stream) {
    const float* feats  = (const float*)d_in[0];
    const float* warped = (const float*)d_in[1];
    float* out = (float*)d_out;
    float* ws  = (float*)d_ws;

    const float inv_n = 1.0f / 65536.0f;   // N fixed by the reference

    dot_partial_kernel<<<BLOCKS, THREADS, 0, stream>>>(
        (const f32x4*)feats, (const f32x4*)warped, ws);
    final_reduce_kernel<<<1, 256, 0, stream>>>(ws, out, BLOCKS, inv_n);
}